// Round 11
// baseline (384.833 us; speedup 1.0000x reference)
//
#include <hip/hip_runtime.h>

// Problem constants (CRF: B=256 seqs, M=1024 steps, D=128 feat, N=26 labels)
#define CB 256
#define CM 1024
#define CD 128
#define CN 26

__device__ inline float rfl_f(float x) {
    return __int_as_float(__builtin_amdgcn_readfirstlane(__float_as_int(x)));
}
__device__ inline float rdl_f(float x, int lane) {
#if __has_builtin(__builtin_amdgcn_readlane)
    return __int_as_float(__builtin_amdgcn_readlane(__float_as_int(x), lane));
#else
    return __shfl(x, lane, 64);
#endif
}
__device__ inline float fexp2(float x) {
#if __has_builtin(__builtin_amdgcn_exp2f)
    return __builtin_amdgcn_exp2f(x);
#else
    return exp2f(x);
#endif
}
__device__ inline float flog2(float x) {
#if __has_builtin(__builtin_amdgcn_logf)
    return __builtin_amdgcn_logf(x);
#else
    return log2f(x);
#endif
}

// ---------------------------------------------------------------------------
// Kernel 1: emissions E[r, a] = log2(e) * dot(X[r, :], W[a, :])
//   + fused unnorm term: usum = sum_i e[i,y_i] + sum_i T[y_{i-1},y_i]
// Round-11 change: R=2 rows/thread, grid 512 -> 2 blocks/CU (8 waves/CU).
// Round-10 (R=4, grid 256) was TLP-starved: 1 wave/SIMD, occupancy 10%,
// VALUBusy 18%, ~60 us of exposed latency over the ~28 us of pipe work.
// R=2 doubles resident waves (latency overlap) at the cost of doubling
// LDS-pipe broadcast reads (8 waves x 832 ds_read_b128/CU); plus 1-chunk
// X ping-pong prefetch (static regs, c-loop unrolled x2) so next-chunk
// VMEM latency hides under the current chunk's ~832 cyc of FMA issue.
// ---------------------------------------------------------------------------
__global__ __launch_bounds__(256, 2) void emit_kernel(
    const float* __restrict__ X, const float* __restrict__ W,
    const int* __restrict__ labels, const float* __restrict__ T,
    float* __restrict__ E, float* __restrict__ out) {
    __shared__ float Ws[CN * CD];  // 13312 B
    __shared__ float rsum[4];

    const int t = threadIdx.x;
    const int row0 = blockIdx.x * 512 + t * 2;

    for (int i = t; i < CN * CD; i += 256) Ws[i] = W[i];
    __syncthreads();

    float acc[2][CN];
#pragma unroll
    for (int g = 0; g < 2; ++g)
#pragma unroll
        for (int a = 0; a < CN; ++a) acc[g][a] = 0.f;

    const float4* __restrict__ x40 =
        reinterpret_cast<const float4*>(X + (size_t)row0 * CD);
    const float4* Ws4 = reinterpret_cast<const float4*>(Ws);

    float4 xa[2][2], xb[2][2];  // ping-pong chunk regs (static indexing)
#pragma unroll
    for (int g = 0; g < 2; ++g) {  // row g is 32 float4 apart
        xa[g][0] = x40[g * 32 + 0];
        xa[g][1] = x40[g * 32 + 1];
    }

#pragma unroll 1
    for (int c = 0; c < 16; c += 2) {  // 8-float k-chunks, unrolled x2
        // prefetch chunk c+1 -> xb (c+1 <= 15 always)
#pragma unroll
        for (int g = 0; g < 2; ++g) {
            xb[g][0] = x40[g * 32 + (c + 1) * 2];
            xb[g][1] = x40[g * 32 + (c + 1) * 2 + 1];
        }
        // compute chunk c from xa
#pragma unroll
        for (int a = 0; a < CN; ++a) {
            float4 w0 = Ws4[a * 32 + c * 2];      // broadcast-uniform addr
            float4 w1 = Ws4[a * 32 + c * 2 + 1];  // -> conflict-free
#pragma unroll
            for (int g = 0; g < 2; ++g) {
                float s = acc[g][a];
                s = fmaf(xa[g][0].x, w0.x, s);
                s = fmaf(xa[g][0].y, w0.y, s);
                s = fmaf(xa[g][0].z, w0.z, s);
                s = fmaf(xa[g][0].w, w0.w, s);
                s = fmaf(xa[g][1].x, w1.x, s);
                s = fmaf(xa[g][1].y, w1.y, s);
                s = fmaf(xa[g][1].z, w1.z, s);
                s = fmaf(xa[g][1].w, w1.w, s);
                acc[g][a] = s;
            }
        }
        // prefetch chunk c+2 -> xa (skip on last iteration)
        if (c + 2 < 16) {
#pragma unroll
            for (int g = 0; g < 2; ++g) {
                xa[g][0] = x40[g * 32 + (c + 2) * 2];
                xa[g][1] = x40[g * 32 + (c + 2) * 2 + 1];
            }
        }
        // compute chunk c+1 from xb
#pragma unroll
        for (int a = 0; a < CN; ++a) {
            float4 w0 = Ws4[a * 32 + (c + 1) * 2];
            float4 w1 = Ws4[a * 32 + (c + 1) * 2 + 1];
#pragma unroll
            for (int g = 0; g < 2; ++g) {
                float s = acc[g][a];
                s = fmaf(xb[g][0].x, w0.x, s);
                s = fmaf(xb[g][0].y, w0.y, s);
                s = fmaf(xb[g][0].z, w0.z, s);
                s = fmaf(xb[g][0].w, w0.w, s);
                s = fmaf(xb[g][1].x, w1.x, s);
                s = fmaf(xb[g][1].y, w1.y, s);
                s = fmaf(xb[g][1].z, w1.z, s);
                s = fmaf(xb[g][1].w, w1.w, s);
                acc[g][a] = s;
            }
        }
    }

    // Store E pre-scaled by log2(e): crf step then needs only exp2(e).
    const float LOG2E = 1.4426950408889634f;
#pragma unroll
    for (int g = 0; g < 2; ++g) {
        float2* e2 =
            reinterpret_cast<float2*>(E + (size_t)(row0 + g) * CN);
#pragma unroll
        for (int a = 0; a < CN / 2; ++a)
            e2[a] = make_float2(acc[g][2 * a] * LOG2E,
                                acc[g][2 * a + 1] * LOG2E);
    }

    // unnorm contribution of this thread's 2 rows (natural-log units).
    float us = 0.f;
#pragma unroll
    for (int g = 0; g < 2; ++g) {
        int row = row0 + g;
        int y = labels[row];
        float sel = acc[g][0];
#pragma unroll
        for (int a = 1; a < CN; ++a) sel = (y == a) ? acc[g][a] : sel;
        us += sel;
        if (row & (CM - 1)) {  // not a sequence start
            int yp = labels[row - 1];
            us += T[yp * CN + y];
        }
    }
#pragma unroll
    for (int off = 32; off > 0; off >>= 1) us += __shfl_xor(us, off, 64);
    if ((t & 63) == 0) rsum[t >> 6] = us;
    __syncthreads();
    if (t == 0)
        atomicAdd(out, (rsum[0] + rsum[1] + rsum[2] + rsum[3]) * (1.f / CB));
}

// ---------------------------------------------------------------------------
// Kernel 2: forward/backward half-chains — EXACT round-6/7 code (~60 us,
// verified across r6/r7/r10). 512 one-wave blocks is this structure's
// optimum (r9's 16-chain packing regressed: 32 CUs active, issue-heavy).
// ---------------------------------------------------------------------------
template <bool BWD>
__device__ void run_half(float* __restrict__ base, const float* __restrict__ T,
                         int a, int l) {
    float AT[CN];
#pragma unroll
    for (int k = 0; k < CN; ++k)
        AT[k] = expf(BWD ? T[a * CN + k] : T[k * CN + a]);

    const int S = BWD ? -CN : CN;  // row stride (descending for backward)
    const float* __restrict__ Eb = base + (BWD ? (size_t)1023 * CN : 0) + a;

    float f, L = 0.f;
    float epf[8];
    const float* pf;
    if (BWD) {
        f = 1.f;  // beta_1023 init; first step consumes row 1023 (offset 0)
#pragma unroll
        for (int k = 0; k < 8; ++k) epf[k] = Eb[k * S];
        pf = Eb + 8 * S;
    } else {
        f = fexp2(Eb[0]);  // consumes row 0 (E in log2 units)
#pragma unroll
        for (int k = 0; k < 8; ++k) epf[k] = Eb[(1 + k) * S];
        pf = Eb + 9 * S;
    }

    auto step = [&](float e_cur, bool renorm) {
        float p = fexp2(e_cur);
        float x = BWD ? p * f : f;  // backward folds p in BEFORE broadcast
        float d0 = 0.f, d1 = 0.f, d2 = 0.f, d3 = 0.f;
#pragma unroll
        for (int b = 0; b < 24; b += 4) {
            d0 = fmaf(AT[b + 0], rdl_f(x, b + 0), d0);
            d1 = fmaf(AT[b + 1], rdl_f(x, b + 1), d1);
            d2 = fmaf(AT[b + 2], rdl_f(x, b + 2), d2);
            d3 = fmaf(AT[b + 3], rdl_f(x, b + 3), d3);
        }
        d0 = fmaf(AT[24], rdl_f(x, 24), d0);
        d1 = fmaf(AT[25], rdl_f(x, 25), d1);
        float d = (d0 + d1) + (d2 + d3);
        f = BWD ? d : p * d;
        if (renorm) {  // exact power-of-2: no rounding error
            float fr = rfl_f(f);
            int k2 = (int)((__float_as_uint(fr) >> 23) & 255) - 127;
            f = ldexpf(f, -k2);
            L += (float)k2;
        }
    };

    // Main: forward 62x8 (steps = rows 1..496), backward 63x8 (t = 0..503).
    const int NMAIN = BWD ? 63 : 62;
    for (int it = 0; it < NMAIN; ++it) {
#pragma unroll
        for (int k = 0; k < 8; ++k) {
            float e_cur = epf[k];
            epf[k] = pf[k * S];  // imm-offset loads (|k*416B| < 4 KB)
            step(e_cur, k == 7);
        }
        pf += 8 * S;
    }
    if (BWD) {
        // Tail: t = 504..511 (renorm at t=511, k==7).
#pragma unroll
        for (int k = 0; k < 8; ++k) step(epf[k], k == 7);
    } else {
        // Tail A: rows 497..504 (renorm at 504); prefetch rows 505..511.
#pragma unroll
        for (int k = 0; k < 8; ++k) {
            float e_cur = epf[k];
            if (k < 7) epf[k] = pf[k * S];
            step(e_cur, k == 7);
        }
        // Tail B: rows 505..511 (7 steps).
#pragma unroll
        for (int k = 0; k < 7; ++k) step(epf[k], false);
    }

    // Final exact renorm so stored components are O(1) and the combine
    // product f*beta cannot overflow.
    {
        float fr = rfl_f(f);
        int k2 = (int)((__float_as_uint(fr) >> 23) & 255) - 127;
        f = ldexpf(f, -k2);
        L += (float)k2;
    }

    // Store interface (cells this block alone has already consumed).
    base[(BWD ? (size_t)1023 * CN : 0) + a] = f;  // lanes>=26 dup-write a=25
    if (l == 0) base[(BWD ? (size_t)1022 * CN : (size_t)CN)] = L;
}

__global__ __launch_bounds__(64) void crf_half_kernel(
    float* __restrict__ E, const float* __restrict__ T) {
    const int s = blockIdx.x >> 1;
    const int l = threadIdx.x;
    const int a = (l < CN) ? l : (CN - 1);
    float* base = E + (size_t)s * CM * CN;
    if (blockIdx.x & 1)
        run_half<true>(base, T, a, l);
    else
        run_half<false>(base, T, a, l);
}

// ---------------------------------------------------------------------------
// Kernel 3: combine — logZ_s = ln2 * (L_f + L_b + log2(sum_a f[a]*beta[a])).
// ---------------------------------------------------------------------------
__global__ __launch_bounds__(64) void crf_combine_kernel(
    const float* __restrict__ E, float* __restrict__ out) {
    const int s = blockIdx.x;
    const int l = threadIdx.x;
    const float LN2 = 0.6931471805599453f;
    const float* base = E + (size_t)s * CM * CN;

    float v = 0.f;
    if (l < CN) v = base[l] * base[(size_t)1023 * CN + l];
#pragma unroll
    for (int off = 32; off > 0; off >>= 1) v += __shfl_xor(v, off, 64);

    if (l == 0) {
        float Lf = base[CN];
        float Lb = base[(size_t)1022 * CN];
        float logZ = LN2 * (Lf + Lb + flog2(v));
        atomicAdd(out, -logZ * (1.f / (float)CB));
    }
}

extern "C" void kernel_launch(void* const* d_in, const int* in_sizes, int n_in,
                              void* d_out, int out_size, void* d_ws,
                              size_t ws_size, hipStream_t stream) {
    const float* X = (const float*)d_in[0];   // [B, M, D]
    const int* labels = (const int*)d_in[1];  // [B, M]
    const float* W = (const float*)d_in[2];   // [N, D]
    const float* T = (const float*)d_in[3];   // [N, N]
    float* out = (float*)d_out;               // scalar
    float* E = (float*)d_ws;                  // [B*M, N] emissions (log2 units)

    hipMemsetAsync(d_out, 0, sizeof(float), stream);
    emit_kernel<<<(CB * CM) / 512, 256, 0, stream>>>(X, W, labels, T, E, out);
    crf_half_kernel<<<CB * 2, 64, 0, stream>>>(E, T);
    crf_combine_kernel<<<CB, 64, 0, stream>>>(E, out);
}

// Round 12
// 276.416 us; speedup vs baseline: 1.3922x; 1.3922x over previous
//
#include <hip/hip_runtime.h>

// Problem constants (CRF: B=256 seqs, M=1024 steps, D=128 feat, N=26 labels)
#define CB 256
#define CM 1024
#define CD 128
#define CN 26

__device__ inline float rfl_f(float x) {
    return __int_as_float(__builtin_amdgcn_readfirstlane(__float_as_int(x)));
}
__device__ inline float rdl_f(float x, int lane) {
#if __has_builtin(__builtin_amdgcn_readlane)
    return __int_as_float(__builtin_amdgcn_readlane(__float_as_int(x), lane));
#else
    return __shfl(x, lane, 64);
#endif
}
__device__ inline float fexp2(float x) {
#if __has_builtin(__builtin_amdgcn_exp2f)
    return __builtin_amdgcn_exp2f(x);
#else
    return exp2f(x);
#endif
}
__device__ inline float flog2(float x) {
#if __has_builtin(__builtin_amdgcn_logf)
    return __builtin_amdgcn_logf(x);
#else
    return log2f(x);
#endif
}

// ---------------------------------------------------------------------------
// Kernel 1: emissions E[r, a] = log2(e) * dot(X[r, :], W[a, :])
//   + fused unnorm term: usum = sum_i e[i,y_i] + sum_i T[y_{i-1},y_i]
// Round-12: R=2 rows/thread, grid 512 (2 blocks/CU, 8 waves/CU), with
// round-10's EXACT inner-loop body (plain per-chunk loads, no ping-pong).
// r10 (R=4, grid 256) was 80% stall: 1 wave/SIMD exposed the ~120-cyc
// ds_read_b128 broadcast latency and per-chunk vmcnt waits. r11 tried
// 2 blocks/CU but its ping-pong + launch_bounds(256,2) spilled (VGPR
// clamped to 128, 260 MB scratch traffic). This version: same TLP fix,
// spill-proof register budget (acc[2][26]=52 + xv 16 = ~75 live VGPRs,
// no cap directive). LDS-pipe/CU doubles (~33 us ceiling) but 2 waves/SIMD
// now hide each other's latency.
// ---------------------------------------------------------------------------
__global__ __launch_bounds__(256) void emit_kernel(
    const float* __restrict__ X, const float* __restrict__ W,
    const int* __restrict__ labels, const float* __restrict__ T,
    float* __restrict__ E, float* __restrict__ out) {
    __shared__ float Ws[CN * CD];  // 13312 B
    __shared__ float rsum[4];

    const int t = threadIdx.x;
    const int row0 = blockIdx.x * 512 + t * 2;

    for (int i = t; i < CN * CD; i += 256) Ws[i] = W[i];
    __syncthreads();

    float acc[2][CN];
#pragma unroll
    for (int g = 0; g < 2; ++g)
#pragma unroll
        for (int a = 0; a < CN; ++a) acc[g][a] = 0.f;

    const float4* __restrict__ x40 =
        reinterpret_cast<const float4*>(X + (size_t)row0 * CD);
    const float4* Ws4 = reinterpret_cast<const float4*>(Ws);

#pragma unroll 1
    for (int c = 0; c < 16; ++c) {  // sixteen 8-float k-chunks of D=128
        float4 xv[2][2];
#pragma unroll
        for (int g = 0; g < 2; ++g) {  // row g = 32 float4 apart
            xv[g][0] = x40[g * 32 + c * 2];
            xv[g][1] = x40[g * 32 + c * 2 + 1];
        }
#pragma unroll
        for (int a = 0; a < CN; ++a) {
            float4 w0 = Ws4[a * 32 + c * 2];      // broadcast-uniform addr
            float4 w1 = Ws4[a * 32 + c * 2 + 1];  // -> conflict-free
#pragma unroll
            for (int g = 0; g < 2; ++g) {
                float s = acc[g][a];
                s = fmaf(xv[g][0].x, w0.x, s);
                s = fmaf(xv[g][0].y, w0.y, s);
                s = fmaf(xv[g][0].z, w0.z, s);
                s = fmaf(xv[g][0].w, w0.w, s);
                s = fmaf(xv[g][1].x, w1.x, s);
                s = fmaf(xv[g][1].y, w1.y, s);
                s = fmaf(xv[g][1].z, w1.z, s);
                s = fmaf(xv[g][1].w, w1.w, s);
                acc[g][a] = s;
            }
        }
    }

    // Store E pre-scaled by log2(e): crf step then needs only exp2(e).
    const float LOG2E = 1.4426950408889634f;
#pragma unroll
    for (int g = 0; g < 2; ++g) {
        float2* e2 =
            reinterpret_cast<float2*>(E + (size_t)(row0 + g) * CN);
#pragma unroll
        for (int a = 0; a < CN / 2; ++a)
            e2[a] = make_float2(acc[g][2 * a] * LOG2E,
                                acc[g][2 * a + 1] * LOG2E);
    }

    // unnorm contribution of this thread's 2 rows (natural-log units).
    float us = 0.f;
#pragma unroll
    for (int g = 0; g < 2; ++g) {
        int row = row0 + g;
        int y = labels[row];
        float sel = acc[g][0];
#pragma unroll
        for (int a = 1; a < CN; ++a) sel = (y == a) ? acc[g][a] : sel;
        us += sel;
        if (row & (CM - 1)) {  // not a sequence start
            int yp = labels[row - 1];
            us += T[yp * CN + y];
        }
    }
#pragma unroll
    for (int off = 32; off > 0; off >>= 1) us += __shfl_xor(us, off, 64);
    if ((t & 63) == 0) rsum[t >> 6] = us;
    __syncthreads();
    if (t == 0)
        atomicAdd(out, (rsum[0] + rsum[1] + rsum[2] + rsum[3]) * (1.f / CB));
}

// ---------------------------------------------------------------------------
// Kernel 2: forward/backward half-chains — EXACT round-6/7/10 code
// (verified ~60 us three times). 512 one-wave blocks is this structure's
// optimum; r9 (16-chain packing) and r4 (grouped readlanes) both regressed.
// ---------------------------------------------------------------------------
template <bool BWD>
__device__ void run_half(float* __restrict__ base, const float* __restrict__ T,
                         int a, int l) {
    float AT[CN];
#pragma unroll
    for (int k = 0; k < CN; ++k)
        AT[k] = expf(BWD ? T[a * CN + k] : T[k * CN + a]);

    const int S = BWD ? -CN : CN;  // row stride (descending for backward)
    const float* __restrict__ Eb = base + (BWD ? (size_t)1023 * CN : 0) + a;

    float f, L = 0.f;
    float epf[8];
    const float* pf;
    if (BWD) {
        f = 1.f;  // beta_1023 init; first step consumes row 1023 (offset 0)
#pragma unroll
        for (int k = 0; k < 8; ++k) epf[k] = Eb[k * S];
        pf = Eb + 8 * S;
    } else {
        f = fexp2(Eb[0]);  // consumes row 0 (E in log2 units)
#pragma unroll
        for (int k = 0; k < 8; ++k) epf[k] = Eb[(1 + k) * S];
        pf = Eb + 9 * S;
    }

    auto step = [&](float e_cur, bool renorm) {
        float p = fexp2(e_cur);
        float x = BWD ? p * f : f;  // backward folds p in BEFORE broadcast
        float d0 = 0.f, d1 = 0.f, d2 = 0.f, d3 = 0.f;
#pragma unroll
        for (int b = 0; b < 24; b += 4) {
            d0 = fmaf(AT[b + 0], rdl_f(x, b + 0), d0);
            d1 = fmaf(AT[b + 1], rdl_f(x, b + 1), d1);
            d2 = fmaf(AT[b + 2], rdl_f(x, b + 2), d2);
            d3 = fmaf(AT[b + 3], rdl_f(x, b + 3), d3);
        }
        d0 = fmaf(AT[24], rdl_f(x, 24), d0);
        d1 = fmaf(AT[25], rdl_f(x, 25), d1);
        float d = (d0 + d1) + (d2 + d3);
        f = BWD ? d : p * d;
        if (renorm) {  // exact power-of-2: no rounding error
            float fr = rfl_f(f);
            int k2 = (int)((__float_as_uint(fr) >> 23) & 255) - 127;
            f = ldexpf(f, -k2);
            L += (float)k2;
        }
    };

    // Main: forward 62x8 (steps = rows 1..496), backward 63x8 (t = 0..503).
    const int NMAIN = BWD ? 63 : 62;
    for (int it = 0; it < NMAIN; ++it) {
#pragma unroll
        for (int k = 0; k < 8; ++k) {
            float e_cur = epf[k];
            epf[k] = pf[k * S];  // imm-offset loads (|k*416B| < 4 KB)
            step(e_cur, k == 7);
        }
        pf += 8 * S;
    }
    if (BWD) {
        // Tail: t = 504..511 (renorm at t=511, k==7).
#pragma unroll
        for (int k = 0; k < 8; ++k) step(epf[k], k == 7);
    } else {
        // Tail A: rows 497..504 (renorm at 504); prefetch rows 505..511.
#pragma unroll
        for (int k = 0; k < 8; ++k) {
            float e_cur = epf[k];
            if (k < 7) epf[k] = pf[k * S];
            step(e_cur, k == 7);
        }
        // Tail B: rows 505..511 (7 steps).
#pragma unroll
        for (int k = 0; k < 7; ++k) step(epf[k], false);
    }

    // Final exact renorm so stored components are O(1) and the combine
    // product f*beta cannot overflow.
    {
        float fr = rfl_f(f);
        int k2 = (int)((__float_as_uint(fr) >> 23) & 255) - 127;
        f = ldexpf(f, -k2);
        L += (float)k2;
    }

    // Store interface (cells this block alone has already consumed).
    base[(BWD ? (size_t)1023 * CN : 0) + a] = f;  // lanes>=26 dup-write a=25
    if (l == 0) base[(BWD ? (size_t)1022 * CN : (size_t)CN)] = L;
}

__global__ __launch_bounds__(64) void crf_half_kernel(
    float* __restrict__ E, const float* __restrict__ T) {
    const int s = blockIdx.x >> 1;
    const int l = threadIdx.x;
    const int a = (l < CN) ? l : (CN - 1);
    float* base = E + (size_t)s * CM * CN;
    if (blockIdx.x & 1)
        run_half<true>(base, T, a, l);
    else
        run_half<false>(base, T, a, l);
}

// ---------------------------------------------------------------------------
// Kernel 3: combine — logZ_s = ln2 * (L_f + L_b + log2(sum_a f[a]*beta[a])).
// ---------------------------------------------------------------------------
__global__ __launch_bounds__(64) void crf_combine_kernel(
    const float* __restrict__ E, float* __restrict__ out) {
    const int s = blockIdx.x;
    const int l = threadIdx.x;
    const float LN2 = 0.6931471805599453f;
    const float* base = E + (size_t)s * CM * CN;

    float v = 0.f;
    if (l < CN) v = base[l] * base[(size_t)1023 * CN + l];
#pragma unroll
    for (int off = 32; off > 0; off >>= 1) v += __shfl_xor(v, off, 64);

    if (l == 0) {
        float Lf = base[CN];
        float Lb = base[(size_t)1022 * CN];
        float logZ = LN2 * (Lf + Lb + flog2(v));
        atomicAdd(out, -logZ * (1.f / (float)CB));
    }
}

extern "C" void kernel_launch(void* const* d_in, const int* in_sizes, int n_in,
                              void* d_out, int out_size, void* d_ws,
                              size_t ws_size, hipStream_t stream) {
    const float* X = (const float*)d_in[0];   // [B, M, D]
    const int* labels = (const int*)d_in[1];  // [B, M]
    const float* W = (const float*)d_in[2];   // [N, D]
    const float* T = (const float*)d_in[3];   // [N, N]
    float* out = (float*)d_out;               // scalar
    float* E = (float*)d_ws;                  // [B*M, N] emissions (log2 units)

    hipMemsetAsync(d_out, 0, sizeof(float), stream);
    emit_kernel<<<(CB * CM) / 512, 256, 0, stream>>>(X, W, labels, T, E, out);
    crf_half_kernel<<<CB * 2, 64, 0, stream>>>(E, T);
    crf_combine_kernel<<<CB, 64, 0, stream>>>(E, out);
}